// Round 1
// baseline (927.218 us; speedup 1.0000x reference)
//
#include <hip/hip_runtime.h>
#include <math.h>

#define B_  8192
#define E_  8
#define D_  3072
#define H_  256
#define C_  100
#define DH_ (D_*H_)
#define HC_ (H_*C_)

// ---------------------------------------------------------------------------
// Generic curve blend: out[e][r] = c0*in[e][0][r] + c1*in[e][1][r], float4-wide
// ---------------------------------------------------------------------------
__global__ void blend4_k(const float4* __restrict__ in, float4* __restrict__ out,
                         const float* __restrict__ coeffs, int inner4, int total4) {
    float c0 = coeffs[0], c1 = coeffs[1];
    for (int i = blockIdx.x * blockDim.x + threadIdx.x; i < total4;
         i += gridDim.x * blockDim.x) {
        int e = i / inner4;
        int r = i - e * inner4;
        const float4* p = in + (size_t)e * 2 * inner4 + r;
        float4 a = p[0];
        float4 b = p[inner4];
        float4 o;
        o.x = c0 * a.x + c1 * b.x;
        o.y = c0 * a.y + c1 * b.y;
        o.z = c0 * a.z + c1 * b.z;
        o.w = c0 * a.w + c1 * b.w;
        out[i] = o;
    }
}

// ---------------------------------------------------------------------------
// Router: fp64 logits (exact argmax), 32 rows/block, 256 threads (1 logit/thr)
// ---------------------------------------------------------------------------
__global__ __launch_bounds__(256) void router_k(
        const float* __restrict__ x, const float* __restrict__ rw,
        const float* __restrict__ rb, const float* __restrict__ coeffs,
        int* __restrict__ idx, int* __restrict__ cnt) {
    __shared__ float  xs[32][33];   // [k][row], padded
    __shared__ double wt[32][8];    // blended router weights (fp64)
    __shared__ double ls[32][8];    // logits
    __shared__ int    scnt[8];
    int t = threadIdx.x;
    double c0 = (double)coeffs[0], c1 = (double)coeffs[1];
    if (t < 8) scnt[t] = 0;
    int row0 = blockIdx.x * 32;
    int r = t & 31;
    int e = t >> 5;
    double acc = 0.0;
    for (int kb = 0; kb < D_; kb += 32) {
        {   // x tile: 32 rows x 32 k = 256 float4
            int rr = t >> 3, q = t & 7;
            float4 v = *(const float4*)(x + (size_t)(row0 + rr) * D_ + kb + q * 4);
            xs[q*4+0][rr] = v.x; xs[q*4+1][rr] = v.y;
            xs[q*4+2][rr] = v.z; xs[q*4+3][rr] = v.w;
        }
        {   // blended W tile in fp64
            int k = t >> 3, ee = t & 7;
            wt[k][ee] = c0 * (double)rw[(size_t)(kb + k) * 8 + ee]
                      + c1 * (double)rw[(size_t)(D_ + kb + k) * 8 + ee];
        }
        __syncthreads();
        #pragma unroll
        for (int k = 0; k < 32; k++)
            acc += (double)xs[k][r] * wt[k][e];
        __syncthreads();
    }
    double be = c0 * (double)rb[e] + c1 * (double)rb[8 + e];
    ls[r][e] = acc + be;
    __syncthreads();
    if (t < 32) {
        double best = ls[t][0];
        int bi = 0;
        #pragma unroll
        for (int ee = 1; ee < 8; ee++) {
            double v = ls[t][ee];
            if (v > best) { best = v; bi = ee; }   // strict > == first-max (np.argmax)
        }
        idx[row0 + t] = bi;
        atomicAdd(&scnt[bi], 1);
    }
    __syncthreads();
    if (t < 8 && scnt[t] > 0) atomicAdd(&cnt[t], scnt[t]);
}

__global__ void offsets_k(const int* __restrict__ cnt, int* __restrict__ off,
                          int* __restrict__ cursor) {
    if (threadIdx.x == 0) {
        int s = 0;
        for (int e = 0; e < E_; e++) { off[e] = s; cursor[e] = s; s += cnt[e]; }
    }
}

__global__ void scatter_k(const int* __restrict__ idx, int* __restrict__ cursor,
                          int* __restrict__ order) {
    int b = blockIdx.x * blockDim.x + threadIdx.x;
    if (b < B_) {
        int e = idx[b];
        int pos = atomicAdd(&cursor[e], 1);
        order[pos] = b;
    }
}

// ---------------------------------------------------------------------------
// Fused expert MLP: grouped GEMM1(+fp64 acc) -> GELU -> GEMM2, 32 rows/block.
// Grid (ceil(B/32), E); blocks past their expert's count exit immediately.
// ---------------------------------------------------------------------------
__global__ __launch_bounds__(256) void mlp_k(
        const float* __restrict__ x, const float* __restrict__ W1b,
        const float* __restrict__ B1b, const float* __restrict__ W2b,
        const float* __restrict__ B2b, const int* __restrict__ order,
        const int* __restrict__ cnt, const int* __restrict__ off,
        float* __restrict__ out) {
    int e = blockIdx.y;
    int ce = cnt[e];
    int tile0 = blockIdx.x * 32;
    if (tile0 >= ce) return;

    __shared__ int   rows[32];
    __shared__ float xs[16][33];    // [BK][BM], padded
    __shared__ float ws[16][260];   // [BK][H], padded to keep float4 align
    __shared__ float hs[32][260];   // h tile for GEMM2

    int t = threadIdx.x;
    if (t < 32) {
        int i = tile0 + t;
        rows[t] = (i < ce) ? order[off[e] + i] : -1;
    }
    __syncthreads();
    int xrow0 = rows[0];

    int tr = t >> 4;                // 0..15 -> rows 2tr, 2tr+1
    int tc = t & 15;                // cols tc*4 + j*64 + m  (j=0..3, m=0..3)
    double accd[2][16];
    #pragma unroll
    for (int i = 0; i < 2; i++)
        #pragma unroll
        for (int j = 0; j < 16; j++) accd[i][j] = 0.0;

    const float* W1e = W1b + (size_t)e * DH_;

    for (int kb = 0; kb < D_; kb += 16) {
        if (t < 128) {  // x tile: 32 rows x 16 k = 128 float4
            int rr = t >> 2, q = t & 3;
            int row = rows[rr];
            if (row < 0) row = xrow0;
            float4 v = *(const float4*)(x + (size_t)row * D_ + kb + q * 4);
            xs[q*4+0][rr] = v.x; xs[q*4+1][rr] = v.y;
            xs[q*4+2][rr] = v.z; xs[q*4+3][rr] = v.w;
        }
        #pragma unroll
        for (int j = 0; j < 4; j++) {  // W1 tile: 16 k x 256 = 1024 float4
            int i4 = t + j * 256;
            int kk = i4 >> 6, c4 = i4 & 63;
            float4 v = *(const float4*)(W1e + (size_t)(kb + kk) * H_ + c4 * 4);
            *(float4*)&ws[kk][c4 * 4] = v;
        }
        __syncthreads();

        float accf[2][16];
        #pragma unroll
        for (int i = 0; i < 2; i++)
            #pragma unroll
            for (int j = 0; j < 16; j++) accf[i][j] = 0.0f;

        #pragma unroll
        for (int kk = 0; kk < 16; kk++) {
            float a0 = xs[kk][2 * tr];
            float a1 = xs[kk][2 * tr + 1];
            #pragma unroll
            for (int j = 0; j < 4; j++) {
                float4 b = *(const float4*)&ws[kk][tc * 4 + j * 64];
                accf[0][4*j+0] += a0 * b.x; accf[1][4*j+0] += a1 * b.x;
                accf[0][4*j+1] += a0 * b.y; accf[1][4*j+1] += a1 * b.y;
                accf[0][4*j+2] += a0 * b.z; accf[1][4*j+2] += a1 * b.z;
                accf[0][4*j+3] += a0 * b.w; accf[1][4*j+3] += a1 * b.w;
            }
        }
        #pragma unroll
        for (int i = 0; i < 2; i++)
            #pragma unroll
            for (int j = 0; j < 16; j++) accd[i][j] += (double)accf[i][j];
        __syncthreads();
    }

    // bias + exact GELU, write h tile
    #pragma unroll
    for (int i = 0; i < 2; i++) {
        int row = 2 * tr + i;
        #pragma unroll
        for (int j = 0; j < 4; j++) {
            #pragma unroll
            for (int m = 0; m < 4; m++) {
                int col = tc * 4 + j * 64 + m;
                float pre = (float)(accd[i][4*j+m] + (double)B1b[e * H_ + col]);
                float h = 0.5f * pre * (1.0f + erff(pre * 0.70710678118654752440f));
                hs[row][col] = h;
            }
        }
    }
    __syncthreads();

    // GEMM2: o[32][100] = hs[32][256] @ W2e[256][100] + B2
    const float* W2e = W2b + (size_t)e * HC_;
    for (int o = t; o < 32 * C_; o += 256) {
        int rr = o / C_;
        int c = o - rr * C_;
        if (rows[rr] < 0) continue;
        float acc = 0.0f;
        #pragma unroll 8
        for (int k = 0; k < H_; k++)
            acc += hs[rr][k] * W2e[k * C_ + c];
        acc += B2b[e * C_ + c];
        out[(size_t)rows[rr] * C_ + c] = acc;
    }
}

// ---------------------------------------------------------------------------
extern "C" void kernel_launch(void* const* d_in, const int* in_sizes, int n_in,
                              void* d_out, int out_size, void* d_ws, size_t ws_size,
                              hipStream_t stream) {
    const float* x        = (const float*)d_in[0];
    const float* coeffs   = (const float*)d_in[1];
    const float* router_w = (const float*)d_in[2];
    const float* router_b = (const float*)d_in[3];
    const float* w1       = (const float*)d_in[4];
    const float* b1       = (const float*)d_in[5];
    const float* w2       = (const float*)d_in[6];
    const float* b2       = (const float*)d_in[7];
    float* out = (float*)d_out;

    // workspace layout (floats/ints)
    float* W1b = (float*)d_ws;                       // E*D*H   = 6291456
    float* W2b = W1b + (size_t)E_ * DH_;             // E*H*C   = 204800
    float* B1b = W2b + (size_t)E_ * HC_;             // E*H     = 2048
    float* B2b = B1b + (size_t)E_ * H_;              // E*C     = 800
    int* idx    = (int*)(B2b + E_ * C_);             // B
    int* order  = idx + B_;                          // B
    int* cnt    = order + B_;                        // 8
    int* off    = cnt + E_;                          // 8
    int* cursor = off + E_;                          // 8

    hipMemsetAsync(cnt, 0, 3 * E_ * sizeof(int), stream);

    blend4_k<<<dim3(1024), 256, 0, stream>>>((const float4*)w1, (float4*)W1b,
                                             coeffs, DH_ / 4, E_ * (DH_ / 4));
    blend4_k<<<dim3(64), 256, 0, stream>>>((const float4*)w2, (float4*)W2b,
                                           coeffs, HC_ / 4, E_ * (HC_ / 4));
    blend4_k<<<dim3(2), 256, 0, stream>>>((const float4*)b1, (float4*)B1b,
                                          coeffs, H_ / 4, E_ * (H_ / 4));
    blend4_k<<<dim3(1), 256, 0, stream>>>((const float4*)b2, (float4*)B2b,
                                          coeffs, C_ / 4, E_ * (C_ / 4));

    router_k<<<dim3(B_ / 32), 256, 0, stream>>>(x, router_w, router_b, coeffs,
                                                idx, cnt);
    offsets_k<<<1, 64, 0, stream>>>(cnt, off, cursor);
    scatter_k<<<dim3(B_ / 256), 256, 0, stream>>>(idx, cursor, order);

    mlp_k<<<dim3(B_ / 32, E_), 256, 0, stream>>>(x, W1b, B1b, W2b, B2b,
                                                 order, cnt, off, out);
}

// Round 2
// 819.487 us; speedup vs baseline: 1.1315x; 1.1315x over previous
//
#include <hip/hip_runtime.h>
#include <math.h>

#define B_  8192
#define E_  8
#define D_  3072
#define H_  256
#define C_  100
#define DH_ (D_*H_)
#define HC_ (H_*C_)

// ---------------------------------------------------------------------------
// Generic curve blend: out[e][r] = c0*in[e][0][r] + c1*in[e][1][r], float4-wide
// ---------------------------------------------------------------------------
__global__ void blend4_k(const float4* __restrict__ in, float4* __restrict__ out,
                         const float* __restrict__ coeffs, int inner4, int total4) {
    float c0 = coeffs[0], c1 = coeffs[1];
    for (int i = blockIdx.x * blockDim.x + threadIdx.x; i < total4;
         i += gridDim.x * blockDim.x) {
        int e = i / inner4;
        int r = i - e * inner4;
        const float4* p = in + (size_t)e * 2 * inner4 + r;
        float4 a = p[0];
        float4 b = p[inner4];
        float4 o;
        o.x = c0 * a.x + c1 * b.x;
        o.y = c0 * a.y + c1 * b.y;
        o.z = c0 * a.z + c1 * b.z;
        o.w = c0 * a.w + c1 * b.w;
        out[i] = o;
    }
}

// ---------------------------------------------------------------------------
// Router: fp64 logits (exact argmax). 16 rows/block, K split 2 ways -> 512
// blocks (2/CU). thread = (r:16, e:8, p:2); p owns one 1536-wide K half.
// ---------------------------------------------------------------------------
__global__ __launch_bounds__(256) void router_k(
        const float* __restrict__ x, const float* __restrict__ rw,
        const float* __restrict__ rb, const float* __restrict__ coeffs,
        int* __restrict__ idx, int* __restrict__ cnt) {
    __shared__ float  xs[2][16][36];    // [half][row][k], padded (144B rows, 16B-aligned)
    __shared__ double wt[2][32][8];     // blended router weights (fp64)
    __shared__ double part[16][8][2];
    __shared__ double ls[16][8];
    __shared__ int    scnt[8];
    int t = threadIdx.x;
    double c0 = (double)coeffs[0], c1 = (double)coeffs[1];
    if (t < 8) scnt[t] = 0;
    int row0 = blockIdx.x * 16;
    int r = t & 15, e = (t >> 4) & 7, p = t >> 7;
    double acc = 0.0;
    for (int kb = 0; kb < 1536; kb += 32) {
        {   // x tile: 2 halves x 16 rows x 32 k = 256 float4, 1/thread
            int h = t >> 7, rr = (t >> 3) & 15, q = t & 7;
            float4 v = *(const float4*)(x + (size_t)(row0 + rr) * D_ + h * 1536 + kb + q * 4);
            *(float4*)&xs[h][rr][q * 4] = v;
        }
        #pragma unroll
        for (int j = 0; j < 2; j++) {   // wt: 512 doubles, 2/thread
            int i = t + j * 256;
            int h = i >> 8, kk = (i >> 3) & 31, ee = i & 7;
            int d = h * 1536 + kb + kk;
            wt[h][kk][ee] = c0 * (double)rw[(size_t)d * 8 + ee]
                          + c1 * (double)rw[(size_t)(D_ + d) * 8 + ee];
        }
        __syncthreads();
        #pragma unroll
        for (int kk = 0; kk < 32; kk++)
            acc += (double)xs[p][r][kk] * wt[p][kk][e];
        __syncthreads();
    }
    part[r][e][p] = acc;
    __syncthreads();
    if (t < 128) {
        int rr = t & 15, ee = t >> 4;
        double be = c0 * (double)rb[ee] + c1 * (double)rb[8 + ee];
        ls[rr][ee] = part[rr][ee][0] + part[rr][ee][1] + be;
    }
    __syncthreads();
    if (t < 16) {
        double best = ls[t][0];
        int bi = 0;
        #pragma unroll
        for (int ee = 1; ee < 8; ee++) {
            double v = ls[t][ee];
            if (v > best) { best = v; bi = ee; }   // strict > == first-max (np.argmax)
        }
        idx[row0 + t] = bi;
        atomicAdd(&scnt[bi], 1);
    }
    __syncthreads();
    if (t < 8 && scnt[t] > 0) atomicAdd(&cnt[t], scnt[t]);
}

__global__ void offsets_k(const int* __restrict__ cnt, int* __restrict__ off,
                          int* __restrict__ cursor) {
    if (threadIdx.x == 0) {
        int s = 0;
        for (int e = 0; e < E_; e++) { off[e] = s; cursor[e] = s; s += cnt[e]; }
    }
}

__global__ void scatter_k(const int* __restrict__ idx, int* __restrict__ cursor,
                          int* __restrict__ order) {
    int b = blockIdx.x * blockDim.x + threadIdx.x;
    if (b < B_) {
        int e = idx[b];
        int pos = atomicAdd(&cursor[e], 1);
        order[pos] = b;
    }
}

// ---------------------------------------------------------------------------
// GEMM1 + GELU: 32 rows x 128 cols (half of H) per block -> ~2x active blocks.
// fp32 chunk-16 accumulation folded into fp64. h written expert-ordered.
// LDS: xs+ws unioned with hstage -> ~21 KB/block.
// ---------------------------------------------------------------------------
__global__ __launch_bounds__(256, 4) void gemm1_k(
        const float* __restrict__ x, const float* __restrict__ W1b,
        const float* __restrict__ B1b, const int* __restrict__ order,
        const int* __restrict__ cnt, const int* __restrict__ off,
        float* __restrict__ hws) {
    int e = blockIdx.z;
    int half = blockIdx.y;
    int ce = cnt[e];
    int tile0 = blockIdx.x * 32;
    if (tile0 >= ce) return;

    __shared__ int rows[32];
    __shared__ float smem[5280];                      // xs[32][33] + ws[32][132]
    float (*xs)[33]      = (float(*)[33])smem;        // [k][row]
    float (*ws)[132]     = (float(*)[132])(smem + 32 * 33);
    float (*hstage)[132] = (float(*)[132])smem;       // aliases xs/ws after K loop

    int t = threadIdx.x;
    if (t < 32) {
        int i = tile0 + t;
        rows[t] = (i < ce) ? order[off[e] + i] : -1;
    }
    __syncthreads();
    int xrow0 = rows[0];

    int tr = t >> 4;            // rows 2tr, 2tr+1
    int tc = t & 15;            // cols tc*4 + j*64 + m, j=0..1
    double accd[2][8];
    #pragma unroll
    for (int i = 0; i < 2; i++)
        #pragma unroll
        for (int j = 0; j < 8; j++) accd[i][j] = 0.0;

    const float* W1e = W1b + (size_t)e * DH_ + half * 128;

    for (int kb = 0; kb < D_; kb += 32) {
        {   // x tile: 32 rows x 32 k = 256 float4, 1/thread (transposed store)
            int rr = t >> 3, q = t & 7;
            int row = rows[rr];
            if (row < 0) row = xrow0;
            float4 v = *(const float4*)(x + (size_t)row * D_ + kb + q * 4);
            xs[q*4+0][rr] = v.x; xs[q*4+1][rr] = v.y;
            xs[q*4+2][rr] = v.z; xs[q*4+3][rr] = v.w;
        }
        #pragma unroll
        for (int j = 0; j < 4; j++) {   // W1 half tile: 32 k x 128 = 1024 float4
            int i4 = t + j * 256;
            int kk = i4 >> 5, c4 = i4 & 31;
            float4 v = *(const float4*)(W1e + (size_t)(kb + kk) * H_ + c4 * 4);
            *(float4*)&ws[kk][c4 * 4] = v;
        }
        __syncthreads();

        #pragma unroll
        for (int h2 = 0; h2 < 2; h2++) {   // two 16-k chunks, fold each into fp64
            float accf[2][8];
            #pragma unroll
            for (int i = 0; i < 2; i++)
                #pragma unroll
                for (int j = 0; j < 8; j++) accf[i][j] = 0.0f;
            #pragma unroll
            for (int kk2 = 0; kk2 < 16; kk2++) {
                int kk = h2 * 16 + kk2;
                float a0 = xs[kk][2 * tr];
                float a1 = xs[kk][2 * tr + 1];
                #pragma unroll
                for (int j = 0; j < 2; j++) {
                    float4 b = *(const float4*)&ws[kk][tc * 4 + j * 64];
                    accf[0][4*j+0] += a0 * b.x; accf[1][4*j+0] += a1 * b.x;
                    accf[0][4*j+1] += a0 * b.y; accf[1][4*j+1] += a1 * b.y;
                    accf[0][4*j+2] += a0 * b.z; accf[1][4*j+2] += a1 * b.z;
                    accf[0][4*j+3] += a0 * b.w; accf[1][4*j+3] += a1 * b.w;
                }
            }
            #pragma unroll
            for (int i = 0; i < 2; i++)
                #pragma unroll
                for (int j = 0; j < 8; j++) accd[i][j] += (double)accf[i][j];
        }
        __syncthreads();
    }

    // bias + exact GELU into hstage (aliases xs/ws; all reads drained by sync)
    int bbase = e * H_ + half * 128;
    #pragma unroll
    for (int i = 0; i < 2; i++) {
        int row = 2 * tr + i;
        #pragma unroll
        for (int j = 0; j < 2; j++) {
            #pragma unroll
            for (int m = 0; m < 4; m++) {
                int col = tc * 4 + j * 64 + m;
                float pre = (float)(accd[i][4*j+m] + (double)B1b[bbase + col]);
                hstage[row][col] = 0.5f * pre * (1.0f + erff(pre * 0.70710678118654752440f));
            }
        }
    }
    __syncthreads();

    // coalesced h write, expert-ordered layout: 32 x 128 = 1024 float4
    size_t p0 = (size_t)off[e] + tile0;
    #pragma unroll
    for (int j = 0; j < 4; j++) {
        int i4 = t + j * 256;
        int rr = i4 >> 5, c4 = i4 & 31;
        if (rows[rr] >= 0)
            *(float4*)(hws + (p0 + rr) * H_ + half * 128 + c4 * 4) =
                *(const float4*)&hstage[rr][c4 * 4];
    }
}

// ---------------------------------------------------------------------------
// GEMM2: 16 ordered rows/block (~520 active blocks), W2 k-tiled through LDS.
// ---------------------------------------------------------------------------
__global__ __launch_bounds__(256) void gemm2_k(
        const float* __restrict__ hws, const float* __restrict__ W2b,
        const float* __restrict__ B2b, const int* __restrict__ order,
        const int* __restrict__ cnt, const int* __restrict__ off,
        float* __restrict__ out) {
    int e = blockIdx.y;
    int ce = cnt[e];
    int tile0 = blockIdx.x * 16;
    if (tile0 >= ce) return;

    __shared__ int rows[16];
    __shared__ float hs[16][260];
    __shared__ float w2s[32][104];
    int t = threadIdx.x;
    if (t < 16) {
        int i = tile0 + t;
        rows[t] = (i < ce) ? order[off[e] + i] : -1;
    }
    int p0 = off[e] + tile0;
    #pragma unroll
    for (int j = 0; j < 4; j++) {   // stage h tile: 16 x 256 = 1024 float4
        int i4 = t + j * 256;
        int rr = i4 >> 6, c4 = i4 & 63;
        int src = p0 + rr;
        if (src >= B_) src = B_ - 1;   // clamp pad rows (never stored)
        *(float4*)&hs[rr][c4 * 4] = *(const float4*)(hws + (size_t)src * H_ + c4 * 4);
    }
    __syncthreads();

    int rr7[7], cc7[7], n = 0;
    for (int o = t; o < 16 * C_; o += 256) {
        rr7[n] = o / C_;
        cc7[n] = o - rr7[n] * C_;
        n++;
    }
    float acc[7] = {0.f, 0.f, 0.f, 0.f, 0.f, 0.f, 0.f};
    const float* W2e = W2b + (size_t)e * HC_;

    for (int kb = 0; kb < H_; kb += 32) {
        for (int i4 = t; i4 < 800; i4 += 256) {   // W2 tile: 32 k x 100 = 800 float4
            int kk = i4 / 25, c4 = i4 - (i4 / 25) * 25;
            *(float4*)&w2s[kk][c4 * 4] = *(const float4*)(W2e + (size_t)(kb + kk) * C_ + c4 * 4);
        }
        __syncthreads();
        for (int i = 0; i < n; i++) {
            int rr = rr7[i], c = cc7[i];
            float a = 0.f;
            #pragma unroll
            for (int kq = 0; kq < 8; kq++) {
                float4 hv = *(const float4*)&hs[rr][kb + kq * 4];
                a += hv.x * w2s[kq*4+0][c] + hv.y * w2s[kq*4+1][c]
                   + hv.z * w2s[kq*4+2][c] + hv.w * w2s[kq*4+3][c];
            }
            acc[i] += a;
        }
        __syncthreads();
    }
    for (int i = 0; i < n; i++) {
        int rr = rr7[i], c = cc7[i];
        if (rows[rr] >= 0)
            out[(size_t)rows[rr] * C_ + c] = acc[i] + B2b[e * C_ + c];
    }
}

// ---------------------------------------------------------------------------
extern "C" void kernel_launch(void* const* d_in, const int* in_sizes, int n_in,
                              void* d_out, int out_size, void* d_ws, size_t ws_size,
                              hipStream_t stream) {
    const float* x        = (const float*)d_in[0];
    const float* coeffs   = (const float*)d_in[1];
    const float* router_w = (const float*)d_in[2];
    const float* router_b = (const float*)d_in[3];
    const float* w1       = (const float*)d_in[4];
    const float* b1       = (const float*)d_in[5];
    const float* w2       = (const float*)d_in[6];
    const float* b2       = (const float*)d_in[7];
    float* out = (float*)d_out;

    // workspace layout (floats/ints), 16B alignment maintained
    float* W1b = (float*)d_ws;                       // E*D*H   = 6291456
    float* W2b = W1b + (size_t)E_ * DH_;             // E*H*C   = 204800
    float* B1b = W2b + (size_t)E_ * HC_;             // E*H     = 2048
    float* B2b = B1b + (size_t)E_ * H_;              // E*C     = 800
    float* hws = B2b + E_ * C_;                      // B*H     = 2097152
    int* idx    = (int*)(hws + (size_t)B_ * H_);     // B
    int* order  = idx + B_;                          // B
    int* cnt    = order + B_;                        // 8
    int* off    = cnt + E_;                          // 8
    int* cursor = off + E_;                          // 8

    hipMemsetAsync(cnt, 0, 3 * E_ * sizeof(int), stream);

    blend4_k<<<dim3(1024), 256, 0, stream>>>((const float4*)w1, (float4*)W1b,
                                             coeffs, DH_ / 4, E_ * (DH_ / 4));
    blend4_k<<<dim3(64), 256, 0, stream>>>((const float4*)w2, (float4*)W2b,
                                           coeffs, HC_ / 4, E_ * (HC_ / 4));
    blend4_k<<<dim3(2), 256, 0, stream>>>((const float4*)b1, (float4*)B1b,
                                          coeffs, H_ / 4, E_ * (H_ / 4));
    blend4_k<<<dim3(1), 256, 0, stream>>>((const float4*)b2, (float4*)B2b,
                                          coeffs, C_ / 4, E_ * (C_ / 4));

    router_k<<<dim3(B_ / 16), 256, 0, stream>>>(x, router_w, router_b, coeffs,
                                                idx, cnt);
    offsets_k<<<1, 64, 0, stream>>>(cnt, off, cursor);
    scatter_k<<<dim3(B_ / 256), 256, 0, stream>>>(idx, cursor, order);

    gemm1_k<<<dim3(B_ / 32, 2, E_), 256, 0, stream>>>(x, W1b, B1b, order, cnt,
                                                      off, hws);
    gemm2_k<<<dim3(B_ / 16, E_), 256, 0, stream>>>(hws, W2b, B2b, order, cnt,
                                                   off, out);
}

// Round 3
// 554.775 us; speedup vs baseline: 1.6713x; 1.4772x over previous
//
#include <hip/hip_runtime.h>
#include <math.h>

#define B_  8192
#define E_  8
#define D_  3072
#define H_  256
#define C_  100
#define DH_ (D_*H_)
#define HC_ (H_*C_)
#define KS_ 4            // K splits in gemm1
#define KSEG_ (D_/KS_)   // 768

typedef __attribute__((ext_vector_type(4))) float f32x4;
typedef __attribute__((ext_vector_type(8))) __bf16 bf16x8;
typedef __attribute__((ext_vector_type(8))) unsigned short ush8;
typedef __attribute__((ext_vector_type(4))) unsigned short ush4;

__device__ inline unsigned short bf16_rne(float f) {
    unsigned u = __builtin_bit_cast(unsigned, f);
    unsigned r = (u + 0x7FFFu + ((u >> 16) & 1u)) >> 16;
    return (unsigned short)r;
}
__device__ inline float bf16_f(unsigned short h) {
    unsigned u = ((unsigned)h) << 16;
    return __builtin_bit_cast(float, u);
}

// ---------------------------------------------------------------------------
// Generic curve blend (w2/b1/b2): out[e][r] = c0*in[e][0][r] + c1*in[e][1][r]
// ---------------------------------------------------------------------------
__global__ void blend4_k(const float4* __restrict__ in, float4* __restrict__ out,
                         const float* __restrict__ coeffs, int inner4, int total4) {
    float c0 = coeffs[0], c1 = coeffs[1];
    for (int i = blockIdx.x * blockDim.x + threadIdx.x; i < total4;
         i += gridDim.x * blockDim.x) {
        int e = i / inner4;
        int r = i - e * inner4;
        const float4* p = in + (size_t)e * 2 * inner4 + r;
        float4 a = p[0];
        float4 b = p[inner4];
        float4 o;
        o.x = c0 * a.x + c1 * b.x;
        o.y = c0 * a.y + c1 * b.y;
        o.z = c0 * a.z + c1 * b.z;
        o.w = c0 * a.w + c1 * b.w;
        out[i] = o;
    }
}

// ---------------------------------------------------------------------------
// W1 blend + bf16 hi/lo split + transpose to [e][h][d] planes.
// Block: 256 thr; lane owns column h = h0+(t&63), d-range (t>>6)*64.. +64.
// Reads coalesced over h; writes 16B/lane chunks (L2 merges 64B lines).
// ---------------------------------------------------------------------------
__global__ __launch_bounds__(256) void blendw1t_k(
        const float* __restrict__ w1, unsigned short* __restrict__ Whi,
        unsigned short* __restrict__ Wlo, const float* __restrict__ coeffs) {
    float c0 = coeffs[0], c1 = coeffs[1];
    int e  = blockIdx.z;
    int h  = blockIdx.y * 64 + (threadIdx.x & 63);
    int d0 = blockIdx.x * 256 + (threadIdx.x >> 6) * 64;
    const float* pa = w1 + ((size_t)(e * 2 + 0) * D_ + d0) * H_ + h;
    const float* pb = w1 + ((size_t)(e * 2 + 1) * D_ + d0) * H_ + h;
    unsigned short* oh = Whi + (size_t)(e * H_ + h) * D_ + d0;
    unsigned short* ol = Wlo + (size_t)(e * H_ + h) * D_ + d0;
    for (int g = 0; g < 8; g++) {           // 8 groups of 8 d
        unsigned short hb[8], lb[8];
        #pragma unroll
        for (int j = 0; j < 8; j++) {
            int dd = g * 8 + j;
            float v = c0 * pa[(size_t)dd * H_] + c1 * pb[(size_t)dd * H_];
            unsigned short hi = bf16_rne(v);
            hb[j] = hi;
            lb[j] = bf16_rne(v - bf16_f(hi));
        }
        *(ush8*)(oh + g * 8) = *(const ush8*)hb;
        *(ush8*)(ol + g * 8) = *(const ush8*)lb;
    }
}

// ---------------------------------------------------------------------------
// Router: fp64 logits (exact argmax). 16 rows/block, K split 2 ways.
// ---------------------------------------------------------------------------
__global__ __launch_bounds__(256) void router_k(
        const float* __restrict__ x, const float* __restrict__ rw,
        const float* __restrict__ rb, const float* __restrict__ coeffs,
        int* __restrict__ idx, int* __restrict__ cnt) {
    __shared__ float  xs[2][16][36];
    __shared__ double wt[2][32][8];
    __shared__ double part[16][8][2];
    __shared__ double ls[16][8];
    __shared__ int    scnt[8];
    int t = threadIdx.x;
    double c0 = (double)coeffs[0], c1 = (double)coeffs[1];
    if (t < 8) scnt[t] = 0;
    int row0 = blockIdx.x * 16;
    int r = t & 15, e = (t >> 4) & 7, p = t >> 7;
    double acc = 0.0;
    for (int kb = 0; kb < 1536; kb += 32) {
        {
            int h = t >> 7, rr = (t >> 3) & 15, q = t & 7;
            float4 v = *(const float4*)(x + (size_t)(row0 + rr) * D_ + h * 1536 + kb + q * 4);
            *(float4*)&xs[h][rr][q * 4] = v;
        }
        #pragma unroll
        for (int j = 0; j < 2; j++) {
            int i = t + j * 256;
            int h = i >> 8, kk = (i >> 3) & 31, ee = i & 7;
            int d = h * 1536 + kb + kk;
            wt[h][kk][ee] = c0 * (double)rw[(size_t)d * 8 + ee]
                          + c1 * (double)rw[(size_t)(D_ + d) * 8 + ee];
        }
        __syncthreads();
        #pragma unroll
        for (int kk = 0; kk < 32; kk++)
            acc += (double)xs[p][r][kk] * wt[p][kk][e];
        __syncthreads();
    }
    part[r][e][p] = acc;
    __syncthreads();
    if (t < 128) {
        int rr = t & 15, ee = t >> 4;
        double be = c0 * (double)rb[ee] + c1 * (double)rb[8 + ee];
        ls[rr][ee] = part[rr][ee][0] + part[rr][ee][1] + be;
    }
    __syncthreads();
    if (t < 16) {
        double best = ls[t][0];
        int bi = 0;
        #pragma unroll
        for (int ee = 1; ee < 8; ee++) {
            double v = ls[t][ee];
            if (v > best) { best = v; bi = ee; }
        }
        idx[row0 + t] = bi;
        atomicAdd(&scnt[bi], 1);
    }
    __syncthreads();
    if (t < 8 && scnt[t] > 0) atomicAdd(&cnt[t], scnt[t]);
}

__global__ void offsets_k(const int* __restrict__ cnt, int* __restrict__ off,
                          int* __restrict__ cursor) {
    if (threadIdx.x == 0) {
        int s = 0;
        for (int e = 0; e < E_; e++) { off[e] = s; cursor[e] = s; s += cnt[e]; }
    }
}

__global__ void scatter_k(const int* __restrict__ idx, int* __restrict__ cursor,
                          int* __restrict__ order) {
    int b = blockIdx.x * blockDim.x + threadIdx.x;
    if (b < B_) {
        int e = idx[b];
        int pos = atomicAdd(&cursor[e], 1);
        order[pos] = b;
    }
}

// ---------------------------------------------------------------------------
// GEMM1 via bf16x2-split MFMA (4 terms: hh, lh, hl, ll), fp32 AGPR acc.
// Block tile: M=64 rows, N=256 (full H), K-extent 768 (KS=4 splits).
// 4 waves: wave w owns cols [w*64, w*64+64) as 4x4 grid of 16x16x32 tiles.
// Partials atomicAdd'ed into hws (zeroed); bias+GELU applied after.
// ---------------------------------------------------------------------------
__global__ __launch_bounds__(256, 2) void gemm1_k(
        const float* __restrict__ x, const unsigned short* __restrict__ Whi,
        const unsigned short* __restrict__ Wlo, const int* __restrict__ order,
        const int* __restrict__ cnt, const int* __restrict__ off,
        float* __restrict__ hws) {
    int e = blockIdx.z;
    int s = blockIdx.y;
    int ce = cnt[e];
    int tile0 = blockIdx.x * 64;
    if (tile0 >= ce) return;

    __shared__ int rows[64];
    __shared__ unsigned short xs_hi[64 * 40];
    __shared__ unsigned short xs_lo[64 * 40];
    __shared__ unsigned short ws_hi[256 * 40];
    __shared__ unsigned short ws_lo[256 * 40];

    int t = threadIdx.x;
    if (t < 64) {
        int i = tile0 + t;
        rows[t] = (i < ce) ? order[off[e] + i] : -1;
    }
    __syncthreads();
    int xrow0 = rows[0];

    int lane = t & 63, w = t >> 6;
    int lr = lane & 15, quad = lane >> 4;
    int kbase = s * KSEG_;

    f32x4 acc[4][4];
    #pragma unroll
    for (int mt = 0; mt < 4; mt++)
        #pragma unroll
        for (int nt = 0; nt < 4; nt++)
            acc[mt][nt] = (f32x4){0.f, 0.f, 0.f, 0.f};

    for (int kb = 0; kb < KSEG_; kb += 32) {
        // ---- stage x tile (64 rows x 32 k), fp32 -> bf16 hi/lo
        #pragma unroll
        for (int it = 0; it < 2; it++) {
            int i = t + it * 256;
            int rr = i >> 3, sg = i & 7;
            int row = rows[rr];
            if (row < 0) row = xrow0;
            float4 v = *(const float4*)(x + (size_t)row * D_ + kbase + kb + sg * 4);
            unsigned short h4[4], l4[4];
            float vv[4] = {v.x, v.y, v.z, v.w};
            #pragma unroll
            for (int j = 0; j < 4; j++) {
                unsigned short hi = bf16_rne(vv[j]);
                h4[j] = hi;
                l4[j] = bf16_rne(vv[j] - bf16_f(hi));
            }
            *(ush4*)&xs_hi[rr * 40 + sg * 4] = *(const ush4*)h4;
            *(ush4*)&xs_lo[rr * 40 + sg * 4] = *(const ush4*)l4;
        }
        // ---- stage W tile (256 cols x 32 k), bf16 planes, direct copy
        #pragma unroll
        for (int it = 0; it < 4; it++) {
            int i = t + it * 256;
            int col = i >> 2, ch = i & 3;
            size_t g = (size_t)(e * H_ + col) * D_ + kbase + kb + ch * 8;
            *(ush8*)&ws_hi[col * 40 + ch * 8] = *(const ush8*)(Whi + g);
            *(ush8*)&ws_lo[col * 40 + ch * 8] = *(const ush8*)(Wlo + g);
        }
        __syncthreads();

        bf16x8 ah[4], al[4], bh[4], bl[4];
        #pragma unroll
        for (int mt = 0; mt < 4; mt++) {
            ah[mt] = __builtin_bit_cast(bf16x8, *(const ush8*)&xs_hi[(mt * 16 + lr) * 40 + quad * 8]);
            al[mt] = __builtin_bit_cast(bf16x8, *(const ush8*)&xs_lo[(mt * 16 + lr) * 40 + quad * 8]);
        }
        #pragma unroll
        for (int nt = 0; nt < 4; nt++) {
            int col = w * 64 + nt * 16 + lr;
            bh[nt] = __builtin_bit_cast(bf16x8, *(const ush8*)&ws_hi[col * 40 + quad * 8]);
            bl[nt] = __builtin_bit_cast(bf16x8, *(const ush8*)&ws_lo[col * 40 + quad * 8]);
        }
        #pragma unroll
        for (int mt = 0; mt < 4; mt++)
            #pragma unroll
            for (int nt = 0; nt < 4; nt++) {
                acc[mt][nt] = __builtin_amdgcn_mfma_f32_16x16x32_bf16(ah[mt], bh[nt], acc[mt][nt], 0, 0, 0);
                acc[mt][nt] = __builtin_amdgcn_mfma_f32_16x16x32_bf16(al[mt], bh[nt], acc[mt][nt], 0, 0, 0);
                acc[mt][nt] = __builtin_amdgcn_mfma_f32_16x16x32_bf16(ah[mt], bl[nt], acc[mt][nt], 0, 0, 0);
                acc[mt][nt] = __builtin_amdgcn_mfma_f32_16x16x32_bf16(al[mt], bl[nt], acc[mt][nt], 0, 0, 0);
            }
        __syncthreads();
    }

    // ---- epilogue: atomic partial accumulate into hws[p][col]
    size_t p0 = (size_t)off[e] + tile0;
    #pragma unroll
    for (int mt = 0; mt < 4; mt++) {
        int rl = mt * 16 + quad * 4;
        #pragma unroll
        for (int nt = 0; nt < 4; nt++) {
            int col = w * 64 + nt * 16 + lr;
            #pragma unroll
            for (int rg = 0; rg < 4; rg++) {
                if (tile0 + rl + rg < ce)
                    atomicAdd(&hws[(p0 + rl + rg) * H_ + col], acc[mt][nt][rg]);
            }
        }
    }
}

// ---------------------------------------------------------------------------
// bias + exact GELU, in place on hws (expert-ordered rows)
// ---------------------------------------------------------------------------
__global__ __launch_bounds__(256) void bias_gelu_k(
        float* __restrict__ hws, const float* __restrict__ B1b,
        const int* __restrict__ order, const int* __restrict__ idx) {
    int gid = blockIdx.x * 256 + threadIdx.x;      // B*H/4 threads
    int p = gid >> 6, c4 = (gid & 63) * 4;
    int e = idx[order[p]];
    float4 v = *(const float4*)(hws + (size_t)p * H_ + c4);
    const float4 bb = *(const float4*)(B1b + e * H_ + c4);
    float pre[4] = {v.x + bb.x, v.y + bb.y, v.z + bb.z, v.w + bb.w};
    float4 o;
    o.x = 0.5f * pre[0] * (1.0f + erff(pre[0] * 0.70710678118654752440f));
    o.y = 0.5f * pre[1] * (1.0f + erff(pre[1] * 0.70710678118654752440f));
    o.z = 0.5f * pre[2] * (1.0f + erff(pre[2] * 0.70710678118654752440f));
    o.w = 0.5f * pre[3] * (1.0f + erff(pre[3] * 0.70710678118654752440f));
    *(float4*)(hws + (size_t)p * H_ + c4) = o;
}

// ---------------------------------------------------------------------------
// GEMM2: 16 ordered rows/block, W2 k-tiled through LDS.
// ---------------------------------------------------------------------------
__global__ __launch_bounds__(256) void gemm2_k(
        const float* __restrict__ hws, const float* __restrict__ W2b,
        const float* __restrict__ B2b, const int* __restrict__ order,
        const int* __restrict__ cnt, const int* __restrict__ off,
        float* __restrict__ out) {
    int e = blockIdx.y;
    int ce = cnt[e];
    int tile0 = blockIdx.x * 16;
    if (tile0 >= ce) return;

    __shared__ int rows[16];
    __shared__ float hs[16][260];
    __shared__ float w2s[32][104];
    int t = threadIdx.x;
    if (t < 16) {
        int i = tile0 + t;
        rows[t] = (i < ce) ? order[off[e] + i] : -1;
    }
    int p0 = off[e] + tile0;
    #pragma unroll
    for (int j = 0; j < 4; j++) {
        int i4 = t + j * 256;
        int rr = i4 >> 6, c4 = i4 & 63;
        int src = p0 + rr;
        if (src >= B_) src = B_ - 1;
        *(float4*)&hs[rr][c4 * 4] = *(const float4*)(hws + (size_t)src * H_ + c4 * 4);
    }
    __syncthreads();

    int rr7[7], cc7[7], n = 0;
    for (int o = t; o < 16 * C_; o += 256) {
        rr7[n] = o / C_;
        cc7[n] = o - rr7[n] * C_;
        n++;
    }
    float acc[7] = {0.f, 0.f, 0.f, 0.f, 0.f, 0.f, 0.f};
    const float* W2e = W2b + (size_t)e * HC_;

    for (int kb = 0; kb < H_; kb += 32) {
        for (int i4 = t; i4 < 800; i4 += 256) {
            int kk = i4 / 25, c4 = i4 - (i4 / 25) * 25;
            *(float4*)&w2s[kk][c4 * 4] = *(const float4*)(W2e + (size_t)(kb + kk) * C_ + c4 * 4);
        }
        __syncthreads();
        for (int i = 0; i < n; i++) {
            int rr = rr7[i], c = cc7[i];
            float a = 0.f;
            #pragma unroll
            for (int kq = 0; kq < 8; kq++) {
                float4 hv = *(const float4*)&hs[rr][kb + kq * 4];
                a += hv.x * w2s[kq*4+0][c] + hv.y * w2s[kq*4+1][c]
                   + hv.z * w2s[kq*4+2][c] + hv.w * w2s[kq*4+3][c];
            }
            acc[i] += a;
        }
        __syncthreads();
    }
    for (int i = 0; i < n; i++) {
        int rr = rr7[i], c = cc7[i];
        if (rows[rr] >= 0)
            out[(size_t)rows[rr] * C_ + c] = acc[i] + B2b[e * C_ + c];
    }
}

// ---------------------------------------------------------------------------
extern "C" void kernel_launch(void* const* d_in, const int* in_sizes, int n_in,
                              void* d_out, int out_size, void* d_ws, size_t ws_size,
                              hipStream_t stream) {
    const float* x        = (const float*)d_in[0];
    const float* coeffs   = (const float*)d_in[1];
    const float* router_w = (const float*)d_in[2];
    const float* router_b = (const float*)d_in[3];
    const float* w1       = (const float*)d_in[4];
    const float* b1       = (const float*)d_in[5];
    const float* w2       = (const float*)d_in[6];
    const float* b2       = (const float*)d_in[7];
    float* out = (float*)d_out;

    // workspace layout (16B alignment maintained)
    unsigned short* Whi = (unsigned short*)d_ws;       // E*H*D bf16 = 12.58 MB
    unsigned short* Wlo = Whi + (size_t)E_ * DH_;      // 12.58 MB
    float* W2b = (float*)(Wlo + (size_t)E_ * DH_);     // E*H*C
    float* B1b = W2b + (size_t)E_ * HC_;               // E*H
    float* B2b = B1b + (size_t)E_ * H_;                // E*C
    float* hws = B2b + E_ * C_;                        // B*H
    int* idx    = (int*)(hws + (size_t)B_ * H_);       // B
    int* order  = idx + B_;                            // B
    int* cnt    = order + B_;                          // 8
    int* off    = cnt + E_;                            // 8
    int* cursor = off + E_;                            // 8

    hipMemsetAsync(cnt, 0, 3 * E_ * sizeof(int), stream);
    hipMemsetAsync(hws, 0, (size_t)B_ * H_ * sizeof(float), stream);

    blendw1t_k<<<dim3(D_ / 256, H_ / 64, E_), 256, 0, stream>>>(w1, Whi, Wlo, coeffs);
    blend4_k<<<dim3(64), 256, 0, stream>>>((const float4*)w2, (float4*)W2b,
                                           coeffs, HC_ / 4, E_ * (HC_ / 4));
    blend4_k<<<dim3(2), 256, 0, stream>>>((const float4*)b1, (float4*)B1b,
                                          coeffs, H_ / 4, E_ * (H_ / 4));
    blend4_k<<<dim3(1), 256, 0, stream>>>((const float4*)b2, (float4*)B2b,
                                          coeffs, C_ / 4, E_ * (C_ / 4));

    router_k<<<dim3(B_ / 16), 256, 0, stream>>>(x, router_w, router_b, coeffs,
                                                idx, cnt);
    offsets_k<<<1, 64, 0, stream>>>(cnt, off, cursor);
    scatter_k<<<dim3(B_ / 256), 256, 0, stream>>>(idx, cursor, order);

    gemm1_k<<<dim3(B_ / 64, KS_, E_), 256, 0, stream>>>(x, Whi, Wlo, order,
                                                        cnt, off, hws);
    bias_gelu_k<<<dim3(B_ * H_ / 4 / 256), 256, 0, stream>>>(hws, B1b, order, idx);
    gemm2_k<<<dim3(B_ / 16, E_), 256, 0, stream>>>(hws, W2b, B2b, order, cnt,
                                                   off, out);
}

// Round 5
// 485.632 us; speedup vs baseline: 1.9093x; 1.1424x over previous
//
#include <hip/hip_runtime.h>
#include <math.h>

#define B_  8192
#define E_  8
#define D_  3072
#define H_  256
#define C_  100
#define CP_ 112          // C padded to 7x16 for MFMA
#define DH_ (D_*H_)
#define HC_ (H_*C_)
#define KS_ 4            // K splits in gemm1
#define KSEG_ (D_/KS_)   // 768
#define RKS_ 4           // K splits in router
#define RSEG_ (D_/RKS_)  // 768

typedef __attribute__((ext_vector_type(4))) float  f32x4;
typedef __attribute__((ext_vector_type(8))) __bf16 bf16x8;
typedef __attribute__((ext_vector_type(8))) unsigned short ush8;
typedef __attribute__((ext_vector_type(4))) unsigned short ush4;

__device__ inline unsigned short bf16_rne(float f) {
    unsigned u = __builtin_bit_cast(unsigned, f);
    unsigned r = (u + 0x7FFFu + ((u >> 16) & 1u)) >> 16;
    return (unsigned short)r;
}
__device__ inline float bf16_f(unsigned short h) {
    unsigned u = ((unsigned)h) << 16;
    return __builtin_bit_cast(float, u);
}

// ---------------------------------------------------------------------------
// Generic curve blend (b1/b2): out[e][r] = c0*in[e][0][r] + c1*in[e][1][r]
// ---------------------------------------------------------------------------
__global__ void blend4_k(const float4* __restrict__ in, float4* __restrict__ out,
                         const float* __restrict__ coeffs, int inner4, int total4) {
    float c0 = coeffs[0], c1 = coeffs[1];
    for (int i = blockIdx.x * blockDim.x + threadIdx.x; i < total4;
         i += gridDim.x * blockDim.x) {
        int e = i / inner4;
        int r = i - e * inner4;
        const float4* p = in + (size_t)e * 2 * inner4 + r;
        float4 a = p[0];
        float4 b = p[inner4];
        float4 o;
        o.x = c0 * a.x + c1 * b.x;
        o.y = c0 * a.y + c1 * b.y;
        o.z = c0 * a.z + c1 * b.z;
        o.w = c0 * a.w + c1 * b.w;
        out[i] = o;
    }
}

// ---------------------------------------------------------------------------
// W1 blend + bf16 hi/lo split + transpose to [e][h][d] planes.
// ---------------------------------------------------------------------------
__global__ __launch_bounds__(256) void blendw1t_k(
        const float* __restrict__ w1, unsigned short* __restrict__ Whi,
        unsigned short* __restrict__ Wlo, const float* __restrict__ coeffs) {
    float c0 = coeffs[0], c1 = coeffs[1];
    int e  = blockIdx.z;
    int h  = blockIdx.y * 64 + (threadIdx.x & 63);
    int d0 = blockIdx.x * 256 + (threadIdx.x >> 6) * 64;
    const float* pa = w1 + ((size_t)(e * 2 + 0) * D_ + d0) * H_ + h;
    const float* pb = w1 + ((size_t)(e * 2 + 1) * D_ + d0) * H_ + h;
    unsigned short* oh = Whi + (size_t)(e * H_ + h) * D_ + d0;
    unsigned short* ol = Wlo + (size_t)(e * H_ + h) * D_ + d0;
    for (int g = 0; g < 8; g++) {
        unsigned short hb[8], lb[8];
        #pragma unroll
        for (int j = 0; j < 8; j++) {
            int dd = g * 8 + j;
            float v = c0 * pa[(size_t)dd * H_] + c1 * pb[(size_t)dd * H_];
            unsigned short hi = bf16_rne(v);
            hb[j] = hi;
            lb[j] = bf16_rne(v - bf16_f(hi));
        }
        *(ush8*)(oh + g * 8) = *(const ush8*)hb;
        *(ush8*)(ol + g * 8) = *(const ush8*)lb;
    }
}

// ---------------------------------------------------------------------------
// W2 blend + bf16 hi/lo split + transpose to [e][c(pad112)][k] planes.
// ---------------------------------------------------------------------------
__global__ __launch_bounds__(256) void blendw2t_k(
        const float* __restrict__ w2, unsigned short* __restrict__ W2thi,
        unsigned short* __restrict__ W2tlo, const float* __restrict__ coeffs) {
    float c0 = coeffs[0], c1 = coeffs[1];
    int c = blockIdx.x, e = blockIdx.y, k = threadIdx.x;
    float v = 0.f;
    if (c < C_)
        v = c0 * w2[((size_t)(e * 2 + 0) * H_ + k) * C_ + c]
          + c1 * w2[((size_t)(e * 2 + 1) * H_ + k) * C_ + c];
    unsigned short hi = bf16_rne(v);
    W2thi[(size_t)(e * CP_ + c) * H_ + k] = hi;
    W2tlo[(size_t)(e * CP_ + c) * H_ + k] = bf16_rne(v - bf16_f(hi));
}

// ---------------------------------------------------------------------------
// Router weight blend -> fp64 [D][8]
// ---------------------------------------------------------------------------
__global__ __launch_bounds__(256) void blendrw_k(
        const float* __restrict__ rw, double* __restrict__ wsd,
        const float* __restrict__ coeffs) {
    double c0 = (double)coeffs[0], c1 = (double)coeffs[1];
    int d = blockIdx.x * 256 + threadIdx.x;
    #pragma unroll
    for (int ee = 0; ee < 8; ee++)
        wsd[(size_t)d * 8 + ee] = c0 * (double)rw[(size_t)d * 8 + ee]
                                + c1 * (double)rw[(size_t)(D_ + d) * 8 + ee];
}

// ---------------------------------------------------------------------------
// Router fp64 GEMV, VALU. 1 wave/block, lane owns a row, 8 fp64 acc in regs.
// W broadcast from LDS (same-address b128 reads = conflict-free broadcast);
// x staged per 32-k tile (1 b32 read per k per lane). Grid (B/64, RKS_).
// ---------------------------------------------------------------------------
__global__ __launch_bounds__(64) void router_v2_k(
        const float* __restrict__ x, const double* __restrict__ wsd,
        double* __restrict__ lpart) {
    __shared__ float  xs[64][33];
    __shared__ double wls[32][8];
    int lane = threadIdx.x;
    int row0 = blockIdx.x * 64;
    int kbase = blockIdx.y * RSEG_;

    double acc[8] = {0, 0, 0, 0, 0, 0, 0, 0};

    for (int kb = 0; kb < RSEG_; kb += 32) {
        #pragma unroll
        for (int it = 0; it < 8; it++) {   // x tile: 64 rows x 32 k = 512 float4
            int i = lane + it * 64;
            int r = i >> 3, c4 = i & 7;
            *(float4*)&xs[r][c4 * 4] =
                *(const float4*)(x + (size_t)(row0 + r) * D_ + kbase + kb + c4 * 4);
        }
        #pragma unroll
        for (int it = 0; it < 4; it++) {   // W tile: 32 k x 8 e doubles
            int i = lane + it * 64;
            int k = i >> 3, ee = i & 7;
            wls[k][ee] = wsd[(size_t)(kbase + kb + k) * 8 + ee];
        }
        __syncthreads();
        #pragma unroll
        for (int kk = 0; kk < 32; kk++) {
            double xv = (double)xs[lane][kk];
            double2 w01 = *(const double2*)&wls[kk][0];
            double2 w23 = *(const double2*)&wls[kk][2];
            double2 w45 = *(const double2*)&wls[kk][4];
            double2 w67 = *(const double2*)&wls[kk][6];
            acc[0] = fma(xv, w01.x, acc[0]);
            acc[1] = fma(xv, w01.y, acc[1]);
            acc[2] = fma(xv, w23.x, acc[2]);
            acc[3] = fma(xv, w23.y, acc[3]);
            acc[4] = fma(xv, w45.x, acc[4]);
            acc[5] = fma(xv, w45.y, acc[5]);
            acc[6] = fma(xv, w67.x, acc[6]);
            acc[7] = fma(xv, w67.y, acc[7]);
        }
        __syncthreads();
    }
    size_t base = ((size_t)blockIdx.y * B_ + row0 + lane) * 8;
    #pragma unroll
    for (int ee = 0; ee < 8; ee++) lpart[base + ee] = acc[ee];
}

// ---------------------------------------------------------------------------
// Combine partials + bias, fp64 argmax (strict > = np first-max), counts.
// ---------------------------------------------------------------------------
__global__ __launch_bounds__(256) void argmax_k(
        const double* __restrict__ lpart, const float* __restrict__ rb,
        const float* __restrict__ coeffs, int* __restrict__ idx,
        int* __restrict__ cnt) {
    __shared__ int scnt[8];
    int t = threadIdx.x;
    if (t < 8) scnt[t] = 0;
    __syncthreads();
    int b = blockIdx.x * 256 + t;
    double c0 = (double)coeffs[0], c1 = (double)coeffs[1];
    double best = -1e300;
    int bi = 0;
    #pragma unroll
    for (int e = 0; e < 8; e++) {
        double l = c0 * (double)rb[e] + c1 * (double)rb[8 + e];
        #pragma unroll
        for (int s2 = 0; s2 < RKS_; s2++)
            l += lpart[((size_t)s2 * B_ + b) * 8 + e];
        if (l > best) { best = l; bi = e; }
    }
    idx[b] = bi;
    atomicAdd(&scnt[bi], 1);
    __syncthreads();
    if (t < 8 && scnt[t] > 0) atomicAdd(&cnt[t], scnt[t]);
}

__global__ void offsets_k(const int* __restrict__ cnt, int* __restrict__ off,
                          int* __restrict__ cursor) {
    if (threadIdx.x == 0) {
        int s = 0;
        for (int e = 0; e < E_; e++) { off[e] = s; cursor[e] = s; s += cnt[e]; }
    }
}

__global__ void scatter_k(const int* __restrict__ idx, int* __restrict__ cursor,
                          int* __restrict__ order) {
    int b = blockIdx.x * blockDim.x + threadIdx.x;
    if (b < B_) {
        int e = idx[b];
        int pos = atomicAdd(&cursor[e], 1);
        order[pos] = b;
    }
}

// ---------------------------------------------------------------------------
// GEMM1 via bf16x2-split MFMA (hh, lh, hl, ll), fp32 AGPR acc.
// M=64, N=256 (full H), K-extent 768 (KS=4). Partials atomicAdd into hws.
// ---------------------------------------------------------------------------
__global__ __launch_bounds__(256, 2) void gemm1_k(
        const float* __restrict__ x, const unsigned short* __restrict__ Whi,
        const unsigned short* __restrict__ Wlo, const int* __restrict__ order,
        const int* __restrict__ cnt, const int* __restrict__ off,
        float* __restrict__ hws) {
    int e = blockIdx.z;
    int s = blockIdx.y;
    int ce = cnt[e];
    int tile0 = blockIdx.x * 64;
    if (tile0 >= ce) return;

    __shared__ int rows[64];
    __shared__ unsigned short xs_hi[64 * 40];
    __shared__ unsigned short xs_lo[64 * 40];
    __shared__ unsigned short ws_hi[256 * 40];
    __shared__ unsigned short ws_lo[256 * 40];

    int t = threadIdx.x;
    if (t < 64) {
        int i = tile0 + t;
        rows[t] = (i < ce) ? order[off[e] + i] : -1;
    }
    __syncthreads();
    int xrow0 = rows[0];

    int lane = t & 63, w = t >> 6;
    int lr = lane & 15, quad = lane >> 4;
    int kbase = s * KSEG_;

    f32x4 acc[4][4];
    #pragma unroll
    for (int mt = 0; mt < 4; mt++)
        #pragma unroll
        for (int nt = 0; nt < 4; nt++)
            acc[mt][nt] = (f32x4){0.f, 0.f, 0.f, 0.f};

    for (int kb = 0; kb < KSEG_; kb += 32) {
        #pragma unroll
        for (int it = 0; it < 2; it++) {
            int i = t + it * 256;
            int rr = i >> 3, sg = i & 7;
            int row = rows[rr];
            if (row < 0) row = xrow0;
            float4 v = *(const float4*)(x + (size_t)row * D_ + kbase + kb + sg * 4);
            unsigned short h4[4], l4[4];
            float vv[4] = {v.x, v.y, v.z, v.w};
            #pragma unroll
            for (int j = 0; j < 4; j++) {
                unsigned short hi = bf16_rne(vv[j]);
                h4[j] = hi;
                l4[j] = bf16_rne(vv[j] - bf16_f(hi));
            }
            *(ush4*)&xs_hi[rr * 40 + sg * 4] = *(const ush4*)h4;
            *(ush4*)&xs_lo[rr * 40 + sg * 4] = *(const ush4*)l4;
        }
        #pragma unroll
        for (int it = 0; it < 4; it++) {
            int i = t + it * 256;
            int col = i >> 2, ch = i & 3;
            size_t g = (size_t)(e * H_ + col) * D_ + kbase + kb + ch * 8;
            *(ush8*)&ws_hi[col * 40 + ch * 8] = *(const ush8*)(Whi + g);
            *(ush8*)&ws_lo[col * 40 + ch * 8] = *(const ush8*)(Wlo + g);
        }
        __syncthreads();

        bf16x8 ah[4], al[4], bh[4], bl[4];
        #pragma unroll
        for (int mt = 0; mt < 4; mt++) {
            ah[mt] = __builtin_bit_cast(bf16x8, *(const ush8*)&xs_hi[(mt * 16 + lr) * 40 + quad * 8]);
            al[mt] = __builtin_bit_cast(bf16x8, *(const ush8*)&xs_lo[(mt * 16 + lr) * 40 + quad * 8]);
        }
        #pragma unroll
        for (int nt = 0; nt < 4; nt++) {
            int col = w * 64 + nt * 16 + lr;
            bh[nt] = __builtin_bit_cast(bf16x8, *(const ush8*)&ws_hi[col * 40 + quad * 8]);
            bl[nt] = __builtin_bit_cast(bf16x8, *(const ush8*)&ws_lo[col * 40 + quad * 8]);
        }
        #pragma unroll
        for (int mt = 0; mt < 4; mt++)
            #pragma unroll
            for (int nt = 0; nt < 4; nt++) {
                acc[mt][nt] = __builtin_amdgcn_mfma_f32_16x16x32_bf16(ah[mt], bh[nt], acc[mt][nt], 0, 0, 0);
                acc[mt][nt] = __builtin_amdgcn_mfma_f32_16x16x32_bf16(al[mt], bh[nt], acc[mt][nt], 0, 0, 0);
                acc[mt][nt] = __builtin_amdgcn_mfma_f32_16x16x32_bf16(ah[mt], bl[nt], acc[mt][nt], 0, 0, 0);
                acc[mt][nt] = __builtin_amdgcn_mfma_f32_16x16x32_bf16(al[mt], bl[nt], acc[mt][nt], 0, 0, 0);
            }
        __syncthreads();
    }

    size_t p0 = (size_t)off[e] + tile0;
    #pragma unroll
    for (int mt = 0; mt < 4; mt++) {
        int rl = mt * 16 + quad * 4;
        #pragma unroll
        for (int nt = 0; nt < 4; nt++) {
            int col = w * 64 + nt * 16 + lr;
            #pragma unroll
            for (int rg = 0; rg < 4; rg++) {
                if (tile0 + rl + rg < ce)
                    atomicAdd(&hws[(p0 + rl + rg) * H_ + col], acc[mt][nt][rg]);
            }
        }
    }
}

// ---------------------------------------------------------------------------
// bias + exact GELU, in place on hws (fp32, expert-ordered rows)
// ---------------------------------------------------------------------------
__global__ __launch_bounds__(256) void bias_gelu_k(
        float* __restrict__ hws, const float* __restrict__ B1b,
        const int* __restrict__ order, const int* __restrict__ idx) {
    int gid = blockIdx.x * 256 + threadIdx.x;
    int p = gid >> 6, c4 = (gid & 63) * 4;
    int e = idx[order[p]];
    float4 v = *(const float4*)(hws + (size_t)p * H_ + c4);
    const float4 bb = *(const float4*)(B1b + e * H_ + c4);
    float pre[4] = {v.x + bb.x, v.y + bb.y, v.z + bb.z, v.w + bb.w};
    float4 o;
    o.x = 0.5f * pre[0] * (1.0f + erff(pre[0] * 0.70710678118654752440f));
    o.y = 0.5f * pre[1] * (1.0f + erff(pre[1] * 0.70710678118654752440f));
    o.z = 0.5f * pre[2] * (1.0f + erff(pre[2] * 0.70710678118654752440f));
    o.w = 0.5f * pre[3] * (1.0f + erff(pre[3] * 0.70710678118654752440f));
    *(float4*)(hws + (size_t)p * H_ + c4) = o;
}

// ---------------------------------------------------------------------------
// GEMM2 via bf16x2-split MFMA; A read fp32 from hws and split in registers,
// B from W2t bf16 planes (L2-resident). Block: 64 rows x 112 cols. No LDS
// except row map. Grid (B/64, E).
// ---------------------------------------------------------------------------
__global__ __launch_bounds__(256) void gemm2_k(
        const float* __restrict__ hws,
        const unsigned short* __restrict__ W2thi, const unsigned short* __restrict__ W2tlo,
        const float* __restrict__ B2b, const int* __restrict__ order,
        const int* __restrict__ cnt, const int* __restrict__ off,
        float* __restrict__ out) {
    int e = blockIdx.y;
    int ce = cnt[e];
    int tile0 = blockIdx.x * 64;
    if (tile0 >= ce) return;

    __shared__ int rows[64];
    int t = threadIdx.x;
    if (t < 64) {
        int i = tile0 + t;
        rows[t] = (i < ce) ? order[off[e] + i] : -1;
    }
    __syncthreads();

    int lane = t & 63, w = t >> 6;
    int m = lane & 15, q = lane >> 4;
    int lr = w * 16 + m;
    int p = off[e] + tile0 + ((tile0 + lr < ce) ? lr : 0);

    f32x4 acc[7];
    #pragma unroll
    for (int nt = 0; nt < 7; nt++) acc[nt] = (f32x4){0.f, 0.f, 0.f, 0.f};

    const unsigned short* w2h = W2thi + (size_t)e * CP_ * H_;
    const unsigned short* w2l = W2tlo + (size_t)e * CP_ * H_;

    #pragma unroll
    for (int s = 0; s < 8; s++) {          // K steps of 32; lane covers k=q*8..+7
        float4 v0 = *(const float4*)(hws + (size_t)p * H_ + s * 32 + q * 8);
        float4 v1 = *(const float4*)(hws + (size_t)p * H_ + s * 32 + q * 8 + 4);
        float f[8] = {v0.x, v0.y, v0.z, v0.w, v1.x, v1.y, v1.z, v1.w};
        unsigned short hh[8], lo[8];
        #pragma unroll
        for (int j = 0; j < 8; j++) {
            unsigned short hi = bf16_rne(f[j]);
            hh[j] = hi;
            lo[j] = bf16_rne(f[j] - bf16_f(hi));
        }
        bf16x8 ah = __builtin_bit_cast(bf16x8, *(const ush8*)hh);
        bf16x8 al = __builtin_bit_cast(bf16x8, *(const ush8*)lo);
        #pragma unroll
        for (int nt = 0; nt < 7; nt++) {
            size_t bo = (size_t)(nt * 16 + m) * H_ + s * 32 + q * 8;
            bf16x8 bh = __builtin_bit_cast(bf16x8, *(const ush8*)(w2h + bo));
            bf16x8 bl = __builtin_bit_cast(bf16x8, *(const ush8*)(w2l + bo));
            acc[nt] = __builtin_amdgcn_mfma_f32_16x16x32_bf16(ah, bh, acc[nt], 0, 0, 0);
            acc[nt] = __builtin_amdgcn_mfma_f32_16x16x32_bf16(al, bh, acc[nt], 0, 0, 0);
            acc[nt] = __builtin_amdgcn_mfma_f32_16x16x32_bf16(ah, bl, acc[nt], 0, 0, 0);
            acc[nt] = __builtin_amdgcn_mfma_f32_16x16x32_bf16(al, bl, acc[nt], 0, 0, 0);
        }
    }

    // D[row][col]: col=m, row=q*4+i (within wave's 16 rows)
    #pragma unroll
    for (int nt = 0; nt < 7; nt++) {
        int c = nt * 16 + m;
        if (c >= C_) continue;
        float bias = B2b[e * C_ + c];
        #pragma unroll
        for (int i = 0; i < 4; i++) {
            int lrow = w * 16 + q * 4 + i;
            if (tile0 + lrow < ce)
                out[(size_t)rows[lrow] * C_ + c] = acc[nt][i] + bias;
        }
    }
}

// ---------------------------------------------------------------------------
extern "C" void kernel_launch(void* const* d_in, const int* in_sizes, int n_in,
                              void* d_out, int out_size, void* d_ws, size_t ws_size,
                              hipStream_t stream) {
    const float* x        = (const float*)d_in[0];
    const float* coeffs   = (const float*)d_in[1];
    const float* router_w = (const float*)d_in[2];
    const float* router_b = (const float*)d_in[3];
    const float* w1       = (const float*)d_in[4];
    const float* b1       = (const float*)d_in[5];
    const float* w2       = (const float*)d_in[6];
    const float* b2       = (const float*)d_in[7];
    float* out = (float*)d_out;

    // workspace layout (16B alignment maintained; total ~33.1 MiB)
    unsigned short* Whi   = (unsigned short*)d_ws;        // E*H*D ush
    unsigned short* Wlo   = Whi + (size_t)E_ * DH_;
    unsigned short* W2thi = Wlo + (size_t)E_ * DH_;       // E*CP*H ush
    unsigned short* W2tlo = W2thi + (size_t)E_ * CP_ * H_;
    double* wsd = (double*)(W2tlo + (size_t)E_ * CP_ * H_);    // D*8 f64
    float* B1b  = (float*)(wsd + (size_t)D_ * 8);         // E*H
    float* B2b  = B1b + (size_t)E_ * H_;                  // E*C
    int* idx    = (int*)(B2b + E_ * C_);                  // B
    int* order  = idx + B_;                               // B
    int* cnt    = order + B_;                             // 8
    int* off    = cnt + E_;                               // 8
    int* cursor = off + E_;                               // 8
    float* hws  = (float*)(cursor + E_);                  // B*H f32
    double* lpart = (double*)hws;                         // RKS*B*8 f64, aliases
                                                          // hws (dead after argmax)

    hipMemsetAsync(cnt, 0, 3 * E_ * sizeof(int), stream);

    blendw1t_k<<<dim3(D_ / 256, H_ / 64, E_), 256, 0, stream>>>(w1, Whi, Wlo, coeffs);
    blendw2t_k<<<dim3(CP_, E_), 256, 0, stream>>>(w2, W2thi, W2tlo, coeffs);
    blend4_k<<<dim3(2), 256, 0, stream>>>((const float4*)b1, (float4*)B1b,
                                          coeffs, H_ / 4, E_ * (H_ / 4));
    blend4_k<<<dim3(1), 256, 0, stream>>>((const float4*)b2, (float4*)B2b,
                                          coeffs, C_ / 4, E_ * (C_ / 4));
    blendrw_k<<<dim3(D_ / 256), 256, 0, stream>>>(router_w, wsd, coeffs);

    router_v2_k<<<dim3(B_ / 64, RKS_), 64, 0, stream>>>(x, wsd, lpart);
    argmax_k<<<dim3(B_ / 256), 256, 0, stream>>>(lpart, router_b, coeffs, idx, cnt);
    offsets_k<<<1, 64, 0, stream>>>(cnt, off, cursor);
    scatter_k<<<dim3(B_ / 256), 256, 0, stream>>>(idx, cursor, order);

    // hws zeroed only now (lpart alias is dead after argmax_k)
    hipMemsetAsync(hws, 0, (size_t)B_ * H_ * sizeof(float), stream);

    gemm1_k<<<dim3(B_ / 64, KS_, E_), 256, 0, stream>>>(x, Whi, Wlo, order,
                                                        cnt, off, hws);
    bias_gelu_k<<<dim3(B_ * H_ / 4 / 256), 256, 0, stream>>>(hws, B1b, order, idx);
    gemm2_k<<<dim3(B_ / 64, E_), 256, 0, stream>>>(hws, W2thi, W2tlo, B2b,
                                                   order, cnt, off, out);
}

// Round 6
// 442.953 us; speedup vs baseline: 2.0933x; 1.0964x over previous
//
#include <hip/hip_runtime.h>
#include <math.h>

#define B_  8192
#define E_  8
#define D_  3072
#define H_  256
#define C_  100
#define DH_ (D_*H_)
#define HC_ (H_*C_)
#define KS_ 8            // K splits in gemm1
#define KSEG_ (D_/KS_)   // 384
#define RKS_ 4           // K splits in router
#define RSEG_ (D_/RKS_)  // 768
#define NTMAX_ 136       // max 64-row tiles over all experts (128+8 slack)

typedef __attribute__((ext_vector_type(4))) float  f32x4;
typedef __attribute__((ext_vector_type(8))) __bf16 bf16x8;
typedef __attribute__((ext_vector_type(8))) unsigned short ush8;
typedef __attribute__((ext_vector_type(4))) unsigned short ush4;

__device__ inline unsigned short bf16_rne(float f) {
    unsigned u = __builtin_bit_cast(unsigned, f);
    unsigned r = (u + 0x7FFFu + ((u >> 16) & 1u)) >> 16;
    return (unsigned short)r;
}
__device__ inline float bf16_f(unsigned short h) {
    unsigned u = ((unsigned)h) << 16;
    return __builtin_bit_cast(float, u);
}

// ---------------------------------------------------------------------------
// Generic curve blend (b1/b2): out[e][r] = c0*in[e][0][r] + c1*in[e][1][r]
// ---------------------------------------------------------------------------
__global__ void blend4_k(const float4* __restrict__ in, float4* __restrict__ out,
                         const float* __restrict__ coeffs, int inner4, int total4) {
    float c0 = coeffs[0], c1 = coeffs[1];
    for (int i = blockIdx.x * blockDim.x + threadIdx.x; i < total4;
         i += gridDim.x * blockDim.x) {
        int e = i / inner4;
        int r = i - e * inner4;
        const float4* p = in + (size_t)e * 2 * inner4 + r;
        float4 a = p[0];
        float4 b = p[inner4];
        float4 o;
        o.x = c0 * a.x + c1 * b.x;
        o.y = c0 * a.y + c1 * b.y;
        o.z = c0 * a.z + c1 * b.z;
        o.w = c0 * a.w + c1 * b.w;
        out[i] = o;
    }
}

// ---------------------------------------------------------------------------
// W1 blend + bf16 hi/lo split + transpose to [e][h][d], via LDS so BOTH
// global reads (over h) and writes (over d) are 256B-contiguous.
// Tile: 64 h x 128 d. Grid (D/128, H/64, E).
// ---------------------------------------------------------------------------
#define TP_ 136   // LDS pitch in ushorts (272 B, 16B-aligned rows)
__global__ __launch_bounds__(256) void blendw1t_k(
        const float* __restrict__ w1, unsigned short* __restrict__ Whi,
        unsigned short* __restrict__ Wlo, const float* __restrict__ coeffs) {
    __shared__ unsigned short thi[64 * TP_];
    __shared__ unsigned short tlo[64 * TP_];
    float c0 = coeffs[0], c1 = coeffs[1];
    int t = threadIdx.x;
    int e = blockIdx.z, h0 = blockIdx.y * 64, d0 = blockIdx.x * 128;
    int h = t & 63, dl = t >> 6;
    const float* pa = w1 + ((size_t)(e * 2 + 0) * D_ + d0) * H_ + h0 + h;
    const float* pb = w1 + ((size_t)(e * 2 + 1) * D_ + d0) * H_ + h0 + h;
    for (int it = 0; it < 32; it++) {
        int d = it * 4 + dl;
        float v = c0 * pa[(size_t)d * H_] + c1 * pb[(size_t)d * H_];
        unsigned short hi = bf16_rne(v);
        thi[h * TP_ + d] = hi;
        tlo[h * TP_ + d] = bf16_rne(v - bf16_f(hi));
    }
    __syncthreads();
    #pragma unroll
    for (int it = 0; it < 4; it++) {
        int i = t + it * 256;
        int hh = i >> 4, d8 = (i & 15) * 8;
        size_t g = (size_t)(e * H_ + h0 + hh) * D_ + d0 + d8;
        *(ush8*)(Whi + g) = *(const ush8*)&thi[hh * TP_ + d8];
        *(ush8*)(Wlo + g) = *(const ush8*)&tlo[hh * TP_ + d8];
    }
}

// ---------------------------------------------------------------------------
// W2 blend + bf16 hi/lo split + transpose to [e][c][k] (stride C_, no pad;
// gemm2's padded-column reads overrun harmlessly into adjacent ws arrays).
// ---------------------------------------------------------------------------
__global__ __launch_bounds__(256) void blendw2t_k(
        const float* __restrict__ w2, unsigned short* __restrict__ W2thi,
        unsigned short* __restrict__ W2tlo, const float* __restrict__ coeffs) {
    float c0 = coeffs[0], c1 = coeffs[1];
    int c = blockIdx.x, e = blockIdx.y, k = threadIdx.x;
    float v = c0 * w2[((size_t)(e * 2 + 0) * H_ + k) * C_ + c]
            + c1 * w2[((size_t)(e * 2 + 1) * H_ + k) * C_ + c];
    unsigned short hi = bf16_rne(v);
    W2thi[(size_t)(e * C_ + c) * H_ + k] = hi;
    W2tlo[(size_t)(e * C_ + c) * H_ + k] = bf16_rne(v - bf16_f(hi));
}

// ---------------------------------------------------------------------------
// Router weight blend -> fp64 [D][8]
// ---------------------------------------------------------------------------
__global__ __launch_bounds__(256) void blendrw_k(
        const float* __restrict__ rw, double* __restrict__ wsd,
        const float* __restrict__ coeffs) {
    double c0 = (double)coeffs[0], c1 = (double)coeffs[1];
    int d = blockIdx.x * 256 + threadIdx.x;
    #pragma unroll
    for (int ee = 0; ee < 8; ee++)
        wsd[(size_t)d * 8 + ee] = c0 * (double)rw[(size_t)d * 8 + ee]
                                + c1 * (double)rw[(size_t)(D_ + d) * 8 + ee];
}

// ---------------------------------------------------------------------------
// Router fp64 GEMV, VALU. 1 wave/block, lane owns a row, 8 fp64 acc in regs.
// ---------------------------------------------------------------------------
__global__ __launch_bounds__(64) void router_v2_k(
        const float* __restrict__ x, const double* __restrict__ wsd,
        double* __restrict__ lpart) {
    __shared__ float  xs[64][33];
    __shared__ double wls[32][8];
    int lane = threadIdx.x;
    int row0 = blockIdx.x * 64;
    int kbase = blockIdx.y * RSEG_;

    double acc[8] = {0, 0, 0, 0, 0, 0, 0, 0};

    for (int kb = 0; kb < RSEG_; kb += 32) {
        #pragma unroll
        for (int it = 0; it < 8; it++) {
            int i = lane + it * 64;
            int r = i >> 3, c4 = i & 7;
            *(float4*)&xs[r][c4 * 4] =
                *(const float4*)(x + (size_t)(row0 + r) * D_ + kbase + kb + c4 * 4);
        }
        #pragma unroll
        for (int it = 0; it < 4; it++) {
            int i = lane + it * 64;
            int k = i >> 3, ee = i & 7;
            wls[k][ee] = wsd[(size_t)(kbase + kb + k) * 8 + ee];
        }
        __syncthreads();
        #pragma unroll
        for (int kk = 0; kk < 32; kk++) {
            double xv = (double)xs[lane][kk];
            double2 w01 = *(const double2*)&wls[kk][0];
            double2 w23 = *(const double2*)&wls[kk][2];
            double2 w45 = *(const double2*)&wls[kk][4];
            double2 w67 = *(const double2*)&wls[kk][6];
            acc[0] = fma(xv, w01.x, acc[0]);
            acc[1] = fma(xv, w01.y, acc[1]);
            acc[2] = fma(xv, w23.x, acc[2]);
            acc[3] = fma(xv, w23.y, acc[3]);
            acc[4] = fma(xv, w45.x, acc[4]);
            acc[5] = fma(xv, w45.y, acc[5]);
            acc[6] = fma(xv, w67.x, acc[6]);
            acc[7] = fma(xv, w67.y, acc[7]);
        }
        __syncthreads();
    }
    size_t base = ((size_t)blockIdx.y * B_ + row0 + lane) * 8;
    #pragma unroll
    for (int ee = 0; ee < 8; ee++) lpart[base + ee] = acc[ee];
}

// ---------------------------------------------------------------------------
// Combine partials + bias, fp64 argmax (strict > = np first-max), counts.
// ---------------------------------------------------------------------------
__global__ __launch_bounds__(256) void argmax_k(
        const double* __restrict__ lpart, const float* __restrict__ rb,
        const float* __restrict__ coeffs, int* __restrict__ idx,
        int* __restrict__ cnt) {
    __shared__ int scnt[8];
    int t = threadIdx.x;
    if (t < 8) scnt[t] = 0;
    __syncthreads();
    int b = blockIdx.x * 256 + t;
    double c0 = (double)coeffs[0], c1 = (double)coeffs[1];
    double best = -1e300;
    int bi = 0;
    #pragma unroll
    for (int e = 0; e < 8; e++) {
        double l = c0 * (double)rb[e] + c1 * (double)rb[8 + e];
        #pragma unroll
        for (int s2 = 0; s2 < RKS_; s2++)
            l += lpart[((size_t)s2 * B_ + b) * 8 + e];
        if (l > best) { best = l; bi = e; }
    }
    idx[b] = bi;
    atomicAdd(&scnt[bi], 1);
    __syncthreads();
    if (t < 8 && scnt[t] > 0) atomicAdd(&cnt[t], scnt[t]);
}

// ---------------------------------------------------------------------------
// Prefix offsets + compact tile map: tmap[i] = (e<<16) | tile0
// ---------------------------------------------------------------------------
__global__ void offsets_k(const int* __restrict__ cnt, int* __restrict__ off,
                          int* __restrict__ cursor, int* __restrict__ tmap,
                          int* __restrict__ ntl) {
    if (threadIdx.x == 0) {
        int s = 0;
        for (int e = 0; e < E_; e++) { off[e] = s; cursor[e] = s; s += cnt[e]; }
        int nt = 0;
        for (int e = 0; e < E_; e++)
            for (int t0 = 0; t0 < cnt[e]; t0 += 64)
                tmap[nt++] = (e << 16) | t0;
        ntl[0] = nt;
    }
}

// order entries pack expert + row: (e<<16) | b
__global__ void scatter_k(const int* __restrict__ idx, int* __restrict__ cursor,
                          int* __restrict__ order) {
    int b = blockIdx.x * blockDim.x + threadIdx.x;
    if (b < B_) {
        int e = idx[b];
        int pos = atomicAdd(&cursor[e], 1);
        order[pos] = (e << 16) | b;
    }
}

// ---------------------------------------------------------------------------
// GEMM1 via bf16x2-split MFMA (hh, lh, hl, ll), fp32 AGPR acc.
// Compact grid (NTMAX, KS): block = one live 64-row tile x one 384-K slice.
// Partials atomicAdd into hws.
// ---------------------------------------------------------------------------
__global__ __launch_bounds__(256, 2) void gemm1_k(
        const float* __restrict__ x, const unsigned short* __restrict__ Whi,
        const unsigned short* __restrict__ Wlo, const int* __restrict__ order,
        const int* __restrict__ cnt, const int* __restrict__ off,
        const int* __restrict__ tmap, const int* __restrict__ ntl,
        float* __restrict__ hws) {
    int tid = blockIdx.x;
    if (tid >= ntl[0]) return;
    int tm = tmap[tid];
    int e = tm >> 16, tile0 = tm & 0xFFFF;
    int ce = cnt[e];
    int s = blockIdx.y;

    __shared__ int rows[64];
    __shared__ unsigned short xs_hi[64 * 40];
    __shared__ unsigned short xs_lo[64 * 40];
    __shared__ unsigned short ws_hi[256 * 40];
    __shared__ unsigned short ws_lo[256 * 40];

    int t = threadIdx.x;
    if (t < 64) {
        int i = tile0 + t;
        rows[t] = (i < ce) ? (order[off[e] + i] & 0xFFFF) : -1;
    }
    __syncthreads();
    int xrow0 = rows[0];

    int lane = t & 63, w = t >> 6;
    int lr = lane & 15, quad = lane >> 4;
    int kbase = s * KSEG_;

    f32x4 acc[4][4];
    #pragma unroll
    for (int mt = 0; mt < 4; mt++)
        #pragma unroll
        for (int nt = 0; nt < 4; nt++)
            acc[mt][nt] = (f32x4){0.f, 0.f, 0.f, 0.f};

    for (int kb = 0; kb < KSEG_; kb += 32) {
        #pragma unroll
        for (int it = 0; it < 2; it++) {
            int i = t + it * 256;
            int rr = i >> 3, sg = i & 7;
            int row = rows[rr];
            if (row < 0) row = xrow0;
            float4 v = *(const float4*)(x + (size_t)row * D_ + kbase + kb + sg * 4);
            unsigned short h4[4], l4[4];
            float vv[4] = {v.x, v.y, v.z, v.w};
            #pragma unroll
            for (int j = 0; j < 4; j++) {
                unsigned short hi = bf16_rne(vv[j]);
                h4[j] = hi;
                l4[j] = bf16_rne(vv[j] - bf16_f(hi));
            }
            *(ush4*)&xs_hi[rr * 40 + sg * 4] = *(const ush4*)h4;
            *(ush4*)&xs_lo[rr * 40 + sg * 4] = *(const ush4*)l4;
        }
        #pragma unroll
        for (int it = 0; it < 4; it++) {
            int i = t + it * 256;
            int col = i >> 2, ch = i & 3;
            size_t g = (size_t)(e * H_ + col) * D_ + kbase + kb + ch * 8;
            *(ush8*)&ws_hi[col * 40 + ch * 8] = *(const ush8*)(Whi + g);
            *(ush8*)&ws_lo[col * 40 + ch * 8] = *(const ush8*)(Wlo + g);
        }
        __syncthreads();

        bf16x8 ah[4], al[4], bh[4], bl[4];
        #pragma unroll
        for (int mt = 0; mt < 4; mt++) {
            ah[mt] = __builtin_bit_cast(bf16x8, *(const ush8*)&xs_hi[(mt * 16 + lr) * 40 + quad * 8]);
            al[mt] = __builtin_bit_cast(bf16x8, *(const ush8*)&xs_lo[(mt * 16 + lr) * 40 + quad * 8]);
        }
        #pragma unroll
        for (int nt = 0; nt < 4; nt++) {
            int col = w * 64 + nt * 16 + lr;
            bh[nt] = __builtin_bit_cast(bf16x8, *(const ush8*)&ws_hi[col * 40 + quad * 8]);
            bl[nt] = __builtin_bit_cast(bf16x8, *(const ush8*)&ws_lo[col * 40 + quad * 8]);
        }
        #pragma unroll
        for (int mt = 0; mt < 4; mt++)
            #pragma unroll
            for (int nt = 0; nt < 4; nt++) {
                acc[mt][nt] = __builtin_amdgcn_mfma_f32_16x16x32_bf16(ah[mt], bh[nt], acc[mt][nt], 0, 0, 0);
                acc[mt][nt] = __builtin_amdgcn_mfma_f32_16x16x32_bf16(al[mt], bh[nt], acc[mt][nt], 0, 0, 0);
                acc[mt][nt] = __builtin_amdgcn_mfma_f32_16x16x32_bf16(ah[mt], bl[nt], acc[mt][nt], 0, 0, 0);
                acc[mt][nt] = __builtin_amdgcn_mfma_f32_16x16x32_bf16(al[mt], bl[nt], acc[mt][nt], 0, 0, 0);
            }
        __syncthreads();
    }

    size_t p0 = (size_t)off[e] + tile0;
    #pragma unroll
    for (int mt = 0; mt < 4; mt++) {
        int rl = mt * 16 + quad * 4;
        #pragma unroll
        for (int nt = 0; nt < 4; nt++) {
            int col = w * 64 + nt * 16 + lr;
            #pragma unroll
            for (int rg = 0; rg < 4; rg++) {
                if (tile0 + rl + rg < ce)
                    atomicAdd(&hws[(p0 + rl + rg) * H_ + col], acc[mt][nt][rg]);
            }
        }
    }
}

// ---------------------------------------------------------------------------
// bias + exact GELU, in place on hws (fp32, expert-ordered rows)
// ---------------------------------------------------------------------------
__global__ __launch_bounds__(256) void bias_gelu_k(
        float* __restrict__ hws, const float* __restrict__ B1b,
        const int* __restrict__ order) {
    int gid = blockIdx.x * 256 + threadIdx.x;
    int p = gid >> 6, c4 = (gid & 63) * 4;
    int e = order[p] >> 16;
    float4 v = *(const float4*)(hws + (size_t)p * H_ + c4);
    const float4 bb = *(const float4*)(B1b + e * H_ + c4);
    float pre[4] = {v.x + bb.x, v.y + bb.y, v.z + bb.z, v.w + bb.w};
    float4 o;
    o.x = 0.5f * pre[0] * (1.0f + erff(pre[0] * 0.70710678118654752440f));
    o.y = 0.5f * pre[1] * (1.0f + erff(pre[1] * 0.70710678118654752440f));
    o.z = 0.5f * pre[2] * (1.0f + erff(pre[2] * 0.70710678118654752440f));
    o.w = 0.5f * pre[3] * (1.0f + erff(pre[3] * 0.70710678118654752440f));
    *(float4*)(hws + (size_t)p * H_ + c4) = o;
}

// ---------------------------------------------------------------------------
// GEMM2 via bf16x2-split MFMA; A split in registers from fp32 hws,
// B from W2t planes (L2-resident). Compact grid (NTMAX).
// ---------------------------------------------------------------------------
__global__ __launch_bounds__(256) void gemm2_k(
        const float* __restrict__ hws,
        const unsigned short* __restrict__ W2thi, const unsigned short* __restrict__ W2tlo,
        const float* __restrict__ B2b, const int* __restrict__ order,
        const int* __restrict__ cnt, const int* __restrict__ off,
        const int* __restrict__ tmap, const int* __restrict__ ntl,
        float* __restrict__ out) {
    int tid = blockIdx.x;
    if (tid >= ntl[0]) return;
    int tm = tmap[tid];
    int e = tm >> 16, tile0 = tm & 0xFFFF;
    int ce = cnt[e];

    __shared__ int rows[64];
    int t = threadIdx.x;
    if (t < 64) {
        int i = tile0 + t;
        rows[t] = (i < ce) ? (order[off[e] + i] & 0xFFFF) : -1;
    }
    __syncthreads();

    int lane = t & 63, w = t >> 6;
    int m = lane & 15, q = lane >> 4;
    int lr = w * 16 + m;
    int p = off[e] + tile0 + ((tile0 + lr < ce) ? lr : 0);

    f32x4 acc[7];
    #pragma unroll
    for (int nt = 0; nt < 7; nt++) acc[nt] = (f32x4){0.f, 0.f, 0.f, 0.f};

    const unsigned short* w2h = W2thi + (size_t)e * C_ * H_;
    const unsigned short* w2l = W2tlo + (size_t)e * C_ * H_;

    #pragma unroll
    for (int s = 0; s < 8; s++) {
        float4 v0 = *(const float4*)(hws + (size_t)p * H_ + s * 32 + q * 8);
        float4 v1 = *(const float4*)(hws + (size_t)p * H_ + s * 32 + q * 8 + 4);
        float f[8] = {v0.x, v0.y, v0.z, v0.w, v1.x, v1.y, v1.z, v1.w};
        unsigned short hh[8], lo[8];
        #pragma unroll
        for (int j = 0; j < 8; j++) {
            unsigned short hi = bf16_rne(f[j]);
            hh[j] = hi;
            lo[j] = bf16_rne(f[j] - bf16_f(hi));
        }
        bf16x8 ah = __builtin_bit_cast(bf16x8, *(const ush8*)hh);
        bf16x8 al = __builtin_bit_cast(bf16x8, *(const ush8*)lo);
        #pragma unroll
        for (int nt = 0; nt < 7; nt++) {
            // cols >= C_ read past the unpadded plane into adjacent ws arrays;
            // results land in discarded lanes only (MFMA cols independent).
            size_t bo = (size_t)(nt * 16 + m) * H_ + s * 32 + q * 8;
            bf16x8 bh = __builtin_bit_cast(bf16x8, *(const ush8*)(w2h + bo));
            bf16x8 bl = __builtin_bit_cast(bf16x8, *(const ush8*)(w2l + bo));
            acc[nt] = __builtin_amdgcn_mfma_f32_16x16x32_bf16(ah, bh, acc[nt], 0, 0, 0);
            acc[nt] = __builtin_amdgcn_mfma_f32_16x16x32_bf16(al, bh, acc[nt], 0, 0, 0);
            acc[nt] = __builtin_amdgcn_mfma_f32_16x16x32_bf16(ah, bl, acc[nt], 0, 0, 0);
            acc[nt] = __builtin_amdgcn_mfma_f32_16x16x32_bf16(al, bl, acc[nt], 0, 0, 0);
        }
    }

    #pragma unroll
    for (int nt = 0; nt < 7; nt++) {
        int c = nt * 16 + m;
        if (c >= C_) continue;
        float bias = B2b[e * C_ + c];
        #pragma unroll
        for (int i = 0; i < 4; i++) {
            int lrow = w * 16 + q * 4 + i;
            if (tile0 + lrow < ce)
                out[(size_t)rows[lrow] * C_ + c] = acc[nt][i] + bias;
        }
    }
}

// ---------------------------------------------------------------------------
extern "C" void kernel_launch(void* const* d_in, const int* in_sizes, int n_in,
                              void* d_out, int out_size, void* d_ws, size_t ws_size,
                              hipStream_t stream) {
    const float* x        = (const float*)d_in[0];
    const float* coeffs   = (const float*)d_in[1];
    const float* router_w = (const float*)d_in[2];
    const float* router_b = (const float*)d_in[3];
    const float* w1       = (const float*)d_in[4];
    const float* b1       = (const float*)d_in[5];
    const float* w2       = (const float*)d_in[6];
    const float* b2       = (const float*)d_in[7];
    float* out = (float*)d_out;

    // workspace layout, total ~34.42 MB (kept under round-2's proven 34.45)
    unsigned short* Whi   = (unsigned short*)d_ws;        // E*H*D ush
    unsigned short* Wlo   = Whi + (size_t)E_ * DH_;
    unsigned short* W2thi = Wlo + (size_t)E_ * DH_;       // E*C*H ush (no pad)
    unsigned short* W2tlo = W2thi + (size_t)E_ * C_ * H_;
    float* B1b  = (float*)(W2tlo + (size_t)E_ * C_ * H_); // E*H
    float* B2b  = B1b + (size_t)E_ * H_;                  // E*C
    int* order  = (int*)(B2b + E_ * C_);                  // B (packed e<<16|b)
    int* cnt    = order + B_;                             // 8
    int* off    = cnt + E_;                               // 8
    int* cursor = off + E_;                               // 8
    int* tmap   = cursor + E_;                            // NTMAX
    int* ntl    = tmap + NTMAX_;                          // 4 (pad to 16B)
    float* hws  = (float*)(ntl + 4);                      // B*H f32
    // transient aliases inside hws (all dead before hws memset):
    double* lpart = (double*)hws;                                  // RKS*B*8 f64 (2.1 MB)
    double* wsd   = (double*)((char*)hws + (size_t)RKS_ * B_ * 8 * 8);  // D*8 f64
    int*    idx   = (int*)((char*)hws + (3u << 20));               // B ints @ +3MB

    hipMemsetAsync(cnt, 0, 3 * E_ * sizeof(int), stream);

    blendw1t_k<<<dim3(D_ / 128, H_ / 64, E_), 256, 0, stream>>>(w1, Whi, Wlo, coeffs);
    blendw2t_k<<<dim3(C_, E_), 256, 0, stream>>>(w2, W2thi, W2tlo, coeffs);
    blend4_k<<<dim3(2), 256, 0, stream>>>((const float4*)b1, (float4*)B1b,
                                          coeffs, H_ / 4, E_ * (H_ / 4));
    blend4_k<<<dim3(1), 256, 0, stream>>>((const float4*)b2, (float4*)B2b,
                                          coeffs, C_ / 4, E_ * (C_ / 4));
    blendrw_k<<<dim3(D_ / 256), 256, 0, stream>>>(router_w, wsd, coeffs);

    router_v2_k<<<dim3(B_ / 64, RKS_), 64, 0, stream>>>(x, wsd, lpart);
    argmax_k<<<dim3(B_ / 256), 256, 0, stream>>>(lpart, router_b, coeffs, idx, cnt);
    offsets_k<<<1, 64, 0, stream>>>(cnt, off, cursor, tmap, ntl);
    scatter_k<<<dim3(B_ / 256), 256, 0, stream>>>(idx, cursor, order);

    // hws zeroed only now (lpart/wsd/idx aliases are dead)
    hipMemsetAsync(hws, 0, (size_t)B_ * H_ * sizeof(float), stream);

    gemm1_k<<<dim3(NTMAX_, KS_), 256, 0, stream>>>(x, Whi, Wlo, order, cnt,
                                                   off, tmap, ntl, hws);
    bias_gelu_k<<<dim3(B_ * H_ / 4 / 256), 256, 0, stream>>>(hws, B1b, order);
    gemm2_k<<<dim3(NTMAX_), 256, 0, stream>>>(hws, W2thi, W2tlo, B2b, order,
                                              cnt, off, tmap, ntl, out);
}